// Round 27
// baseline (68.405 us; speedup 1.0000x reference)
//
#include <hip/hip_runtime.h>
#include <math.h>

// ManifoldHyperConnectionFuse on MI355X — R26: e-major weight layout.
// R25: occupancy 63% = NULL (double-null with R20) -> not wave-starved.
// Capacity check missed until now: wt = 48KB > L1 32KB, and the e-loop
// sweeps it as 8 streams of stride 2KB -> L1 THRASH, every w-load = L2 trip.
// R26 = R24 (best, 67.9us) with wt reordered to [e][24][128]: per iteration
// the block reads ONE contiguous 6KB chunk, sequential across e -> pure
// streaming, L1-friendly. Only prep dst + twp indexing change.

#define NTOK 16

typedef __attribute__((ext_vector_type(2))) _Float16 h2v;

__device__ __forceinline__ float fdot2f(unsigned int a, unsigned int b, float c) {
#if __has_builtin(__builtin_amdgcn_fdot2)
    return __builtin_amdgcn_fdot2(__builtin_bit_cast(h2v, a),
                                  __builtin_bit_cast(h2v, b), c, false);
#else
    h2v av = __builtin_bit_cast(h2v, a);
    h2v bv = __builtin_bit_cast(h2v, b);
    return fmaf((float)av[1], (float)bv[1],
           fmaf((float)av[0], (float)bv[0], c));
#endif
}

__device__ __forceinline__ unsigned int pk_f16(float a, float b) {
    const auto p = __builtin_amdgcn_cvt_pkrtz(a, b);   // __fp16x2
    return __builtin_bit_cast(unsigned int, p);
}

__device__ __forceinline__ float sigmoid_f(float z) {
    return 1.0f / (1.0f + __expf(-z));
}

// sum over each aligned 16-lane row via DPP row_ror (VALU-only)
__device__ __forceinline__ float row16_sum(float x) {
    x += __int_as_float(__builtin_amdgcn_update_dpp(
        0, __float_as_int(x), 0x121, 0xf, 0xf, false)); // row_ror:1
    x += __int_as_float(__builtin_amdgcn_update_dpp(
        0, __float_as_int(x), 0x122, 0xf, 0xf, false)); // row_ror:2
    x += __int_as_float(__builtin_amdgcn_update_dpp(
        0, __float_as_int(x), 0x124, 0xf, 0xf, false)); // row_ror:4
    x += __int_as_float(__builtin_amdgcn_update_dpp(
        0, __float_as_int(x), 0x128, 0xf, 0xf, false)); // row_ror:8
    return x;
}

// ---- prep: fold alpha*nw*w -> f16 wt2[e][24][128] (e-major) in d_ws ----
// e = k>>7 (8 chunks of 128 k), inner: [n][k&127]
__global__ __launch_bounds__(256)
void prep_kernel(const float* __restrict__ nw,
                 const float* __restrict__ w,
                 const float* __restrict__ alpha,
                 unsigned short* __restrict__ wt)
{
    const int tid = blockIdx.x * 256 + threadIdx.x;   // 6144 threads
    const int flat = 4 * tid;                          // w is [k][n], flat=k*24+n
    const float4 w4 = *(const float4*)(w + flat);
    const float a0 = alpha[0], a1 = alpha[1], a2 = alpha[2];
    const float vals[4] = {w4.x, w4.y, w4.z, w4.w};
    #pragma unroll
    for (int c = 0; c < 4; ++c) {
        const int f = flat + c;
        const int k = f / 24;
        const int n = f - 24 * k;
        const float as = (n < 4) ? a0 : ((n < 8) ? a1 : a2);
        const unsigned int p = pk_f16(as * nw[k] * vals[c], 0.f);
        wt[(k >> 7) * 3072 + n * 128 + (k & 127)] = (unsigned short)(p & 0xffffu);
    }
}

__global__ __launch_bounds__(256, 3)
void mhc_kernel(const float* __restrict__ h,
                const unsigned short* __restrict__ wt,
                const float* __restrict__ beta,
                float* __restrict__ out)
{
    const int tid  = threadIdx.x;
    const int lane = tid & 63;
    const int wv   = tid >> 6;     // wave id: owns tokens [4wv, 4wv+4)
    const int ksl  = lane & 15;    // k-slice lane
    const int ng   = lane >> 4;    // n-group (6 n's each)

    __shared__ unsigned int tile[NTOK * 512];  // f16 x-tile, 32KB
    __shared__ float Hpart[NTOK][28];          // [0:24) H, [24] r2
    __shared__ float smalls[NTOK][26];         // Hpre, Hpost, P

    const long tok0 = (long)blockIdx.x * NTOK;

    // ---- stage: 16 rows, f32 -> f16 pack, 64KB read -> 32KB LDS ----
    {
        const float* src = h + tok0 * 1024 + 4 * tid;
        #pragma unroll
        for (int i = 0; i < NTOK; ++i) {
            const float4 v = *(const float4*)(src + 1024 * i);
            uint2 u;
            u.x = pk_f16(v.x, v.y);
            u.y = pk_f16(v.z, v.w);
            *(uint2*)(tile + i * 512 + 2 * tid) = u;
        }
    }
    __syncthreads();

    // ---- phase A: 4 tokens/wave, b128 loads, 8 e-iters, fdot2 MACs ----
    const int t0 = 4 * wv;
    const uint4* txp = (const uint4*)tile + t0 * 128 + ksl;
    // e-major wt: uint4 idx = e*384 + (6*ng + j)*16 + ksl
    const uint4* twp = (const uint4*)wt + (6 * ng) * 16 + ksl;

    float acc[4][6], r2[4];
    #pragma unroll
    for (int t = 0; t < 4; ++t) {
        r2[t] = 0.f;
        #pragma unroll
        for (int j = 0; j < 6; ++j) acc[t][j] = 0.f;
    }

    #pragma unroll 1
    for (int e = 0; e < 8; ++e) {
        uint4 xw[4];
        #pragma unroll
        for (int t = 0; t < 4; ++t) xw[t] = txp[t * 128 + e * 16];   // LDS b128
        uint4 wr[6];
        #pragma unroll
        for (int j = 0; j < 6; ++j) wr[j] = twp[e * 384 + j * 16];   // streaming

        #pragma unroll
        for (int j = 0; j < 6; ++j) {
            #pragma unroll
            for (int t = 0; t < 4; ++t) {
                float a = acc[t][j];
                a = fdot2f(xw[t].x, wr[j].x, a);
                a = fdot2f(xw[t].y, wr[j].y, a);
                a = fdot2f(xw[t].z, wr[j].z, a);
                a = fdot2f(xw[t].w, wr[j].w, a);
                acc[t][j] = a;
            }
        }
        #pragma unroll
        for (int t = 0; t < 4; ++t) {
            float r = r2[t];
            r = fdot2f(xw[t].x, xw[t].x, r);
            r = fdot2f(xw[t].y, xw[t].y, r);
            r = fdot2f(xw[t].z, xw[t].z, r);
            r = fdot2f(xw[t].w, xw[t].w, r);
            r2[t] = r;
        }
    }

    // ---- DPP reduce over ksl -> FINAL H for this wave's 4 tokens ----
    #pragma unroll
    for (int t = 0; t < 4; ++t) {
        #pragma unroll
        for (int j = 0; j < 6; ++j) acc[t][j] = row16_sum(acc[t][j]);
        r2[t] = row16_sum(r2[t]);
    }
    if (ksl == 0) {
        #pragma unroll
        for (int t = 0; t < 4; ++t) {
            #pragma unroll
            for (int j = 0; j < 6; ++j)
                Hpart[t0 + t][6 * ng + j] = acc[t][j];
            if (ng == 0) Hpart[t0 + t][24] = r2[t];
        }
    }
    __syncthreads();

    // ---- scalar phase: lanes 0..15, one token each (R2-proven) ----
    if (tid < NTOK) {
        const int t = tid;
        float Hp[24];
        #pragma unroll
        for (int q = 0; q < 24; ++q) Hp[q] = Hpart[t][q];
        const float r2v = Hpart[t][24];
        const float r_ = 1.0f / (sqrtf(r2v) * 0.03125f + 1e-6f);

        float Hpre[4], Hpost[4], K[16];
        #pragma unroll
        for (int n = 0; n < 4; ++n)
            Hpre[n] = sigmoid_f(fmaf(r_, Hp[n], beta[n]));
        #pragma unroll
        for (int n = 0; n < 4; ++n)
            Hpost[n] = 2.0f * sigmoid_f(fmaf(r_, Hp[4 + n], beta[4 + n]));
        #pragma unroll
        for (int q = 0; q < 16; ++q)
            K[q] = __expf(fmaf(r_, Hp[8 + q], beta[8 + q]));

        float u0=1.f,u1=1.f,u2=1.f,u3=1.f;
        float v0=1.f,v1=1.f,v2=1.f,v3=1.f;
        for (int itr = 0; itr < 10; ++itr) {
            u0 = 1.0f/(K[0]*v0  + K[1]*v1  + K[2]*v2  + K[3]*v3  + 1e-8f);
            u1 = 1.0f/(K[4]*v0  + K[5]*v1  + K[6]*v2  + K[7]*v3  + 1e-8f);
            u2 = 1.0f/(K[8]*v0  + K[9]*v1  + K[10]*v2 + K[11]*v3 + 1e-8f);
            u3 = 1.0f/(K[12]*v0 + K[13]*v1 + K[14]*v2 + K[15]*v3 + 1e-8f);
            v0 = 1.0f/(K[0]*u0  + K[4]*u1  + K[8]*u2  + K[12]*u3 + 1e-8f);
            v1 = 1.0f/(K[1]*u0  + K[5]*u1  + K[9]*u2  + K[13]*u3 + 1e-8f);
            v2 = 1.0f/(K[2]*u0  + K[6]*u1  + K[10]*u2 + K[14]*u3 + 1e-8f);
            v3 = 1.0f/(K[3]*u0  + K[7]*u1  + K[11]*u2 + K[15]*u3 + 1e-8f);
        }
        smalls[t][0] = Hpre[0];  smalls[t][1] = Hpre[1];
        smalls[t][2] = Hpre[2];  smalls[t][3] = Hpre[3];
        smalls[t][4] = Hpost[0]; smalls[t][5] = Hpost[1];
        smalls[t][6] = Hpost[2]; smalls[t][7] = Hpost[3];
        smalls[t][8]  = u0*K[0]*v0;   smalls[t][9]  = u0*K[1]*v1;
        smalls[t][10] = u0*K[2]*v2;   smalls[t][11] = u0*K[3]*v3;
        smalls[t][12] = u1*K[4]*v0;   smalls[t][13] = u1*K[5]*v1;
        smalls[t][14] = u1*K[6]*v2;   smalls[t][15] = u1*K[7]*v3;
        smalls[t][16] = u2*K[8]*v0;   smalls[t][17] = u2*K[9]*v1;
        smalls[t][18] = u2*K[10]*v2;  smalls[t][19] = u2*K[11]*v3;
        smalls[t][20] = u3*K[12]*v0;  smalls[t][21] = u3*K[13]*v1;
        smalls[t][22] = u3*K[14]*v2;  smalls[t][23] = u3*K[15]*v3;
    }
    __syncthreads();

    // ---- phase C: x from f16 tile (no global h re-read) ----
    const int gg = wv;   // n = gg, d = 4*lane..+3
    for (int it = 0; it < NTOK; ++it) {
        const uint2* tl = (const uint2*)tile + it * 256 + lane;
        float xm[4][4];
        #pragma unroll
        for (int m = 0; m < 4; ++m) {
            const uint2 u = tl[m * 64];
            const h2v p0 = __builtin_bit_cast(h2v, u.x);
            const h2v p1 = __builtin_bit_cast(h2v, u.y);
            xm[m][0] = (float)p0[0]; xm[m][1] = (float)p0[1];
            xm[m][2] = (float)p1[0]; xm[m][3] = (float)p1[1];
        }

        const float hp0 = smalls[it][0], hp1 = smalls[it][1];
        const float hp2 = smalls[it][2], hp3 = smalls[it][3];
        const float hpost = smalls[it][4 + gg];
        const float P0 = smalls[it][8 + 4*gg + 0];
        const float P1 = smalls[it][8 + 4*gg + 1];
        const float P2 = smalls[it][8 + 4*gg + 2];
        const float P3 = smalls[it][8 + 4*gg + 3];

        float4 o;
        #pragma unroll
        for (int c = 0; c < 4; ++c) {
            const float hpre = hp0*xm[0][c] + hp1*xm[1][c]
                             + hp2*xm[2][c] + hp3*xm[3][c];
            const float res  = P0*xm[0][c] + P1*xm[1][c]
                             + P2*xm[2][c] + P3*xm[3][c];
            ((float*)&o)[c] = fmaf(hpost, hpre, res);
        }
        *(float4*)(out + (tok0 + it) * 1024 + gg * 256 + 4 * lane) = o;
    }
}

extern "C" void kernel_launch(void* const* d_in, const int* in_sizes, int n_in,
                              void* d_out, int out_size, void* d_ws, size_t ws_size,
                              hipStream_t stream) {
    const float* h     = (const float*)d_in[0];
    const float* nw    = (const float*)d_in[1];
    const float* w     = (const float*)d_in[2];
    const float* alpha = (const float*)d_in[3];
    const float* beta  = (const float*)d_in[4];
    float* out = (float*)d_out;
    unsigned short* wt = (unsigned short*)d_ws;   // 24*1024*2B = 48KB

    prep_kernel<<<24, 256, 0, stream>>>(nw, w, alpha, wt);
    // 32768 tokens / 16 per block = 2048 blocks
    mhc_kernel<<<2048, 256, 0, stream>>>(h, wt, beta, out);
}

// Round 28
// 67.537 us; speedup vs baseline: 1.0129x; 1.0129x over previous
//
#include <hip/hip_runtime.h>
#include <math.h>

// ManifoldHyperConnectionFuse on MI355X — R27: R24 with the e-loop UNROLLED.
// R26 (e-major layout) = NULL -> w-caching not the binder. Null ledger:
// occupancy x3, barriers, w-layout, tile-vs-global, weight-traffic. Only
// win: b128 = fewer serial exposure windows (-11%). Corollary: duration
// tracks exposure-event count -> let the compiler pipeline ACROSS
// iterations. Every phase-A loop since R7 carried '#pragma unroll 1'
// (obsolete weight-residency armor). R27 deletes it: the scheduler can
// hoist iteration e+1's 10 loads above e's 112 fdot2s. One-line A/B.

#define NTOK 16

typedef __attribute__((ext_vector_type(2))) _Float16 h2v;

__device__ __forceinline__ float fdot2f(unsigned int a, unsigned int b, float c) {
#if __has_builtin(__builtin_amdgcn_fdot2)
    return __builtin_amdgcn_fdot2(__builtin_bit_cast(h2v, a),
                                  __builtin_bit_cast(h2v, b), c, false);
#else
    h2v av = __builtin_bit_cast(h2v, a);
    h2v bv = __builtin_bit_cast(h2v, b);
    return fmaf((float)av[1], (float)bv[1],
           fmaf((float)av[0], (float)bv[0], c));
#endif
}

__device__ __forceinline__ unsigned int pk_f16(float a, float b) {
    const auto p = __builtin_amdgcn_cvt_pkrtz(a, b);   // __fp16x2
    return __builtin_bit_cast(unsigned int, p);
}

__device__ __forceinline__ float sigmoid_f(float z) {
    return 1.0f / (1.0f + __expf(-z));
}

// sum over each aligned 16-lane row via DPP row_ror (VALU-only)
__device__ __forceinline__ float row16_sum(float x) {
    x += __int_as_float(__builtin_amdgcn_update_dpp(
        0, __float_as_int(x), 0x121, 0xf, 0xf, false)); // row_ror:1
    x += __int_as_float(__builtin_amdgcn_update_dpp(
        0, __float_as_int(x), 0x122, 0xf, 0xf, false)); // row_ror:2
    x += __int_as_float(__builtin_amdgcn_update_dpp(
        0, __float_as_int(x), 0x124, 0xf, 0xf, false)); // row_ror:4
    x += __int_as_float(__builtin_amdgcn_update_dpp(
        0, __float_as_int(x), 0x128, 0xf, 0xf, false)); // row_ror:8
    return x;
}

// ---- prep: fold alpha*nw*w -> f16 wt[24][1024] (n-major) in d_ws ----
__global__ __launch_bounds__(256)
void prep_kernel(const float* __restrict__ nw,
                 const float* __restrict__ w,
                 const float* __restrict__ alpha,
                 unsigned short* __restrict__ wt)
{
    const int tid = blockIdx.x * 256 + threadIdx.x;   // 6144 threads
    const int flat = 4 * tid;                          // w is [k][n], flat=k*24+n
    const float4 w4 = *(const float4*)(w + flat);
    const float a0 = alpha[0], a1 = alpha[1], a2 = alpha[2];
    const float vals[4] = {w4.x, w4.y, w4.z, w4.w};
    #pragma unroll
    for (int c = 0; c < 4; ++c) {
        const int f = flat + c;
        const int k = f / 24;
        const int n = f - 24 * k;
        const float as = (n < 4) ? a0 : ((n < 8) ? a1 : a2);
        const unsigned int p = pk_f16(as * nw[k] * vals[c], 0.f);
        wt[n * 1024 + k] = (unsigned short)(p & 0xffffu);
    }
}

__global__ __launch_bounds__(256, 3)
void mhc_kernel(const float* __restrict__ h,
                const unsigned short* __restrict__ wt,
                const float* __restrict__ beta,
                float* __restrict__ out)
{
    const int tid  = threadIdx.x;
    const int lane = tid & 63;
    const int wv   = tid >> 6;     // wave id: owns tokens [4wv, 4wv+4)
    const int ksl  = lane & 15;    // k-slice lane
    const int ng   = lane >> 4;    // n-group (6 n's each)

    __shared__ unsigned int tile[NTOK * 512];  // f16 x-tile, 32KB
    __shared__ float Hpart[NTOK][28];          // [0:24) H, [24] r2
    __shared__ float smalls[NTOK][26];         // Hpre, Hpost, P

    const long tok0 = (long)blockIdx.x * NTOK;

    // ---- stage: 16 rows, f32 -> f16 pack, 64KB read -> 32KB LDS ----
    {
        const float* src = h + tok0 * 1024 + 4 * tid;
        #pragma unroll
        for (int i = 0; i < NTOK; ++i) {
            const float4 v = *(const float4*)(src + 1024 * i);
            uint2 u;
            u.x = pk_f16(v.x, v.y);
            u.y = pk_f16(v.z, v.w);
            *(uint2*)(tile + i * 512 + 2 * tid) = u;
        }
    }
    __syncthreads();

    // ---- phase A: 4 tokens/wave, b128 loads, 8 e-iters (COMPILER-UNROLLED) ----
    const int t0 = 4 * wv;
    const uint4* txp = (const uint4*)tile + t0 * 128 + ksl;
    const uint4* twp = (const uint4*)wt + (6 * ng) * 128 + ksl;

    float acc[4][6], r2[4];
    #pragma unroll
    for (int t = 0; t < 4; ++t) {
        r2[t] = 0.f;
        #pragma unroll
        for (int j = 0; j < 6; ++j) acc[t][j] = 0.f;
    }

    #pragma unroll
    for (int e = 0; e < 8; ++e) {
        uint4 xw[4];
        #pragma unroll
        for (int t = 0; t < 4; ++t) xw[t] = txp[t * 128 + e * 16];   // LDS b128
        uint4 wr[6];
        #pragma unroll
        for (int j = 0; j < 6; ++j) wr[j] = twp[j * 128 + e * 16];   // L2 b128

        #pragma unroll
        for (int j = 0; j < 6; ++j) {
            #pragma unroll
            for (int t = 0; t < 4; ++t) {
                float a = acc[t][j];
                a = fdot2f(xw[t].x, wr[j].x, a);
                a = fdot2f(xw[t].y, wr[j].y, a);
                a = fdot2f(xw[t].z, wr[j].z, a);
                a = fdot2f(xw[t].w, wr[j].w, a);
                acc[t][j] = a;
            }
        }
        #pragma unroll
        for (int t = 0; t < 4; ++t) {
            float r = r2[t];
            r = fdot2f(xw[t].x, xw[t].x, r);
            r = fdot2f(xw[t].y, xw[t].y, r);
            r = fdot2f(xw[t].z, xw[t].z, r);
            r = fdot2f(xw[t].w, xw[t].w, r);
            r2[t] = r;
        }
    }

    // ---- DPP reduce over ksl -> FINAL H for this wave's 4 tokens ----
    #pragma unroll
    for (int t = 0; t < 4; ++t) {
        #pragma unroll
        for (int j = 0; j < 6; ++j) acc[t][j] = row16_sum(acc[t][j]);
        r2[t] = row16_sum(r2[t]);
    }
    if (ksl == 0) {
        #pragma unroll
        for (int t = 0; t < 4; ++t) {
            #pragma unroll
            for (int j = 0; j < 6; ++j)
                Hpart[t0 + t][6 * ng + j] = acc[t][j];
            if (ng == 0) Hpart[t0 + t][24] = r2[t];
        }
    }
    __syncthreads();

    // ---- scalar phase: lanes 0..15, one token each (R2-proven) ----
    if (tid < NTOK) {
        const int t = tid;
        float Hp[24];
        #pragma unroll
        for (int q = 0; q < 24; ++q) Hp[q] = Hpart[t][q];
        const float r2v = Hpart[t][24];
        const float r_ = 1.0f / (sqrtf(r2v) * 0.03125f + 1e-6f);

        float Hpre[4], Hpost[4], K[16];
        #pragma unroll
        for (int n = 0; n < 4; ++n)
            Hpre[n] = sigmoid_f(fmaf(r_, Hp[n], beta[n]));
        #pragma unroll
        for (int n = 0; n < 4; ++n)
            Hpost[n] = 2.0f * sigmoid_f(fmaf(r_, Hp[4 + n], beta[4 + n]));
        #pragma unroll
        for (int q = 0; q < 16; ++q)
            K[q] = __expf(fmaf(r_, Hp[8 + q], beta[8 + q]));

        float u0=1.f,u1=1.f,u2=1.f,u3=1.f;
        float v0=1.f,v1=1.f,v2=1.f,v3=1.f;
        for (int itr = 0; itr < 10; ++itr) {
            u0 = 1.0f/(K[0]*v0  + K[1]*v1  + K[2]*v2  + K[3]*v3  + 1e-8f);
            u1 = 1.0f/(K[4]*v0  + K[5]*v1  + K[6]*v2  + K[7]*v3  + 1e-8f);
            u2 = 1.0f/(K[8]*v0  + K[9]*v1  + K[10]*v2 + K[11]*v3 + 1e-8f);
            u3 = 1.0f/(K[12]*v0 + K[13]*v1 + K[14]*v2 + K[15]*v3 + 1e-8f);
            v0 = 1.0f/(K[0]*u0  + K[4]*u1  + K[8]*u2  + K[12]*u3 + 1e-8f);
            v1 = 1.0f/(K[1]*u0  + K[5]*u1  + K[9]*u2  + K[13]*u3 + 1e-8f);
            v2 = 1.0f/(K[2]*u0  + K[6]*u1  + K[10]*u2 + K[14]*u3 + 1e-8f);
            v3 = 1.0f/(K[3]*u0  + K[7]*u1  + K[11]*u2 + K[15]*u3 + 1e-8f);
        }
        smalls[t][0] = Hpre[0];  smalls[t][1] = Hpre[1];
        smalls[t][2] = Hpre[2];  smalls[t][3] = Hpre[3];
        smalls[t][4] = Hpost[0]; smalls[t][5] = Hpost[1];
        smalls[t][6] = Hpost[2]; smalls[t][7] = Hpost[3];
        smalls[t][8]  = u0*K[0]*v0;   smalls[t][9]  = u0*K[1]*v1;
        smalls[t][10] = u0*K[2]*v2;   smalls[t][11] = u0*K[3]*v3;
        smalls[t][12] = u1*K[4]*v0;   smalls[t][13] = u1*K[5]*v1;
        smalls[t][14] = u1*K[6]*v2;   smalls[t][15] = u1*K[7]*v3;
        smalls[t][16] = u2*K[8]*v0;   smalls[t][17] = u2*K[9]*v1;
        smalls[t][18] = u2*K[10]*v2;  smalls[t][19] = u2*K[11]*v3;
        smalls[t][20] = u3*K[12]*v0;  smalls[t][21] = u3*K[13]*v1;
        smalls[t][22] = u3*K[14]*v2;  smalls[t][23] = u3*K[15]*v3;
    }
    __syncthreads();

    // ---- phase C: x from f16 tile (no global h re-read) ----
    const int gg = wv;   // n = gg, d = 4*lane..+3
    for (int it = 0; it < NTOK; ++it) {
        const uint2* tl = (const uint2*)tile + it * 256 + lane;
        float xm[4][4];
        #pragma unroll
        for (int m = 0; m < 4; ++m) {
            const uint2 u = tl[m * 64];
            const h2v p0 = __builtin_bit_cast(h2v, u.x);
            const h2v p1 = __builtin_bit_cast(h2v, u.y);
            xm[m][0] = (float)p0[0]; xm[m][1] = (float)p0[1];
            xm[m][2] = (float)p1[0]; xm[m][3] = (float)p1[1];
        }

        const float hp0 = smalls[it][0], hp1 = smalls[it][1];
        const float hp2 = smalls[it][2], hp3 = smalls[it][3];
        const float hpost = smalls[it][4 + gg];
        const float P0 = smalls[it][8 + 4*gg + 0];
        const float P1 = smalls[it][8 + 4*gg + 1];
        const float P2 = smalls[it][8 + 4*gg + 2];
        const float P3 = smalls[it][8 + 4*gg + 3];

        float4 o;
        #pragma unroll
        for (int c = 0; c < 4; ++c) {
            const float hpre = hp0*xm[0][c] + hp1*xm[1][c]
                             + hp2*xm[2][c] + hp3*xm[3][c];
            const float res  = P0*xm[0][c] + P1*xm[1][c]
                             + P2*xm[2][c] + P3*xm[3][c];
            ((float*)&o)[c] = fmaf(hpost, hpre, res);
        }
        *(float4*)(out + (tok0 + it) * 1024 + gg * 256 + 4 * lane) = o;
    }
}

extern "C" void kernel_launch(void* const* d_in, const int* in_sizes, int n_in,
                              void* d_out, int out_size, void* d_ws, size_t ws_size,
                              hipStream_t stream) {
    const float* h     = (const float*)d_in[0];
    const float* nw    = (const float*)d_in[1];
    const float* w     = (const float*)d_in[2];
    const float* alpha = (const float*)d_in[3];
    const float* beta  = (const float*)d_in[4];
    float* out = (float*)d_out;
    unsigned short* wt = (unsigned short*)d_ws;   // 24*1024*2B = 48KB

    prep_kernel<<<24, 256, 0, stream>>>(nw, w, alpha, wt);
    // 32768 tokens / 16 per block = 2048 blocks
    mhc_kernel<<<2048, 256, 0, stream>>>(h, wt, beta, out);
}